// Round 7
// baseline (666.742 us; speedup 1.0000x reference)
//
#include <hip/hip_runtime.h>

#define FLTMAX 3.402823466e+38f

// ---------------------------------------------------------------------------
// Geometry:
//   Layer1: B=1024, N=784, Np=896, S=7, F=512, I=8, K=4
//   Layer2: B=1024, N=512, Np=512, S=4, F=10,  I=8, K=4
// Layer-1: persistent-grid kernel (1024 blocks co-resident at
// __launch_bounds__(256,4)); per plane s: compute 128x128 acc (bit-exact
// fmaf chain) -> block min/max -> device atomics -> distributed throttled
// grid barrier -> in-register 5-bit ADC quant -> LDS stage -> TILE-MAJOR
// contiguous uint8 stores.
//
// R6 post-mortem: WRITE_SIZE stuck at ~4x Pidx (470-535MB for 117MB) across
// THREE different store schemes; mm1 wall time = write-drain at 1.25TB/s.
// The one invariant: Pidx rows (2048B) were split 128B-per-block across 16
// blocks -> inter-block line interleaving defeats TCC write combining
// (partial-line masked DRAM writes, >=64B counted/executed per 16B req).
// R0's clean stores wrote 512B-contiguous-per-block. Fix: tile-major Pidx
// [tile=((s*8+i)*16+colgrp)*8+btile][16KB contiguous per block-plane] —
// each wave store = 1KB contiguous, block writes a private 16KB burst.
// fold1 addressing updated to match; values bit-identical.
//
// Barrier (R6, kept): arrivals on 8 counters in separate 64B lines; block 0
// detects and writes a release flag; s_sleep throttling; vmcnt(0) before
// arrival orders the stats atomics; all stats reads via RELAXED AGENT
// atomic loads (coherence point past the non-coherent per-XCD L2) — no
// fences (R3: fences = L2 flush storms).
// ---------------------------------------------------------------------------

// bar layout (unsigned words): plane s: 8 arrival counters at [s*128 + j*16]
// (64B apart); release flag at [896 + s*16]. Total 1008 words.
__device__ __forceinline__ void grid_barrier(unsigned* bar, int s, unsigned nblk)
{
    __syncthreads();
    if (threadIdx.x == 0) {
        unsigned* ctr = bar + s * 128;
        unsigned* rel = bar + 896 + s * 16;
        // drain this wave's outstanding VMEM (incl. the stats atomics) so
        // they are complete at the coherence point before we signal.
        asm volatile("s_waitcnt vmcnt(0)" ::: "memory");
        __hip_atomic_fetch_add(&ctr[(blockIdx.x & 7) << 4], 1u,
                               __ATOMIC_RELAXED, __HIP_MEMORY_SCOPE_AGENT);
        if (blockIdx.x == 0) {
            // detector: poll the 8 distributed counters at ~0.25us period
            for (int it = 0; it < (1 << 20); ++it) {
                unsigned tot = 0;
#pragma unroll
                for (int j = 0; j < 8; ++j)
                    tot += __hip_atomic_load(&ctr[j << 4], __ATOMIC_RELAXED,
                                             __HIP_MEMORY_SCOPE_AGENT);
                if (tot >= nblk) break;
                __builtin_amdgcn_s_sleep(8);
            }
            __hip_atomic_store(rel, 1u, __ATOMIC_RELAXED, __HIP_MEMORY_SCOPE_AGENT);
        } else {
            // waiters: poll the once-written release flag at ~0.6us period
            for (int it = 0; it < (1 << 20); ++it) {
                if (__hip_atomic_load(rel, __ATOMIC_RELAXED,
                                      __HIP_MEMORY_SCOPE_AGENT) != 0u)
                    break;
                __builtin_amdgcn_s_sleep(16);
            }
        }
    }
    __syncthreads();
}

// Fused: xq codes (row in LDS) -> sx1 row sum + bit-packed planes xqbT[i][w][b].
// Also initializes stats1 + barrier region.
__global__ void prep1_kernel(const float* __restrict__ x, float* __restrict__ sx1,
                             unsigned* __restrict__ xqbT, unsigned* __restrict__ stats1,
                             unsigned* __restrict__ bar)
{
    __shared__ float xr[896];
    __shared__ float red[128];
    int b = blockIdx.x;
    if (b == 0) {
        for (int t = threadIdx.x; t < 224; t += 128) {
            stats1[t * 2] = 0x7F7FFFFFu; stats1[t * 2 + 1] = 0u;
        }
        for (int t = threadIdx.x; t < 1008; t += 128) bar[t] = 0u;
    }
    float psum = 0.f;
    for (int n = threadIdx.x; n < 896; n += 128) {
        float v = 0.f;
        if (n < 784) {
            float xv = x[b * 784 + n];
            xv = fminf(fmaxf(xv, 0.f), 1.f);
            v = rintf(__fmul_rn(xv, 255.f));
        }
        xr[n] = v;
        psum += v;  // integer-valued, exact in any order
    }
    red[threadIdx.x] = psum;
    __syncthreads();
    for (int w = 64; w >= 1; w >>= 1) {
        if (threadIdx.x < w) red[threadIdx.x] += red[threadIdx.x + w];
        __syncthreads();
    }
    if (threadIdx.x == 0) sx1[b] = red[0];
    if (threadIdx.x < 28) {
        int w = threadIdx.x;
        unsigned words[8] = {0, 0, 0, 0, 0, 0, 0, 0};
#pragma unroll 8
        for (int n = 0; n < 32; ++n) {
            int v = (int)xr[w * 32 + n];
#pragma unroll
            for (int i = 0; i < 8; ++i) words[i] |= ((unsigned)((v >> i) & 1)) << n;
        }
#pragma unroll
        for (int i = 0; i < 8; ++i) xqbT[(i * 28 + w) * 1024 + b] = words[i];
    }
}

// Fused conductance-prep + transpose: writes g1t[n][k*512+f] directly.
__global__ void prepg1t_kernel(const float* __restrict__ w1, const float* __restrict__ noise1,
                               float* __restrict__ g1t)
{
    __shared__ float t[4][32][33];
    const int n0 = blockIdx.x * 32, f0 = blockIdx.y * 32;
    const int tid = threadIdx.x;
    {
        int n = tid & 31, fi = tid >> 5;
#pragma unroll
        for (int p = 0; p < 4; ++p) {
            int f = p * 8 + fi;
            int gn = n0 + n, gf = f0 + f;
            float gv[4] = {0.f, 0.f, 0.f, 0.f};
            if (gn < 784) {
                float w = w1[gf * 784 + gn];
                float Xi = fminf(fmaxf(rintf(__fmul_rn(__fmul_rn(__fadd_rn(w, 1.f), 0.5f), 255.f)),
                                       0.f), 255.f);
                int xi = (int)Xi;
                float4 nz = *(const float4*)&noise1[(gf * 896 + gn) * 4];
                float nzv[4] = {nz.x, nz.y, nz.z, nz.w};
#pragma unroll
                for (int k = 0; k < 4; ++k) {
                    int slc = (xi >> (2 * k)) & 3;
                    float base = __fadd_rn(__fmul_rn((float)slc, 0.9f), 0.3f);
                    float nf = __fadd_rn(1.f, __fmul_rn(0.05f, nzv[k]));
                    gv[k] = __fmul_rn(base, nf);
                }
            }
#pragma unroll
            for (int k = 0; k < 4; ++k) t[k][n][f] = gv[k];
        }
    }
    __syncthreads();
    {
        int f = tid & 31, nn = tid >> 5;
#pragma unroll
        for (int p = 0; p < 4; ++p) {
            int n = p * 8 + nn;
#pragma unroll
            for (int k = 0; k < 4; ++k)
                g1t[(n0 + n) * 2048 + k * 512 + f0 + f] = t[k][n][f];
        }
    }
}

// g2t[n][k][f] layout for layer-2 matmul
__global__ void prepg2_kernel(const float* __restrict__ w3, const float* __restrict__ noise3,
                              float* __restrict__ g2t)
{
    int gid = blockIdx.x * 256 + threadIdx.x;
    if (gid >= 10 * 512) return;
    int f = gid / 512, n = gid % 512;
    float w = w3[f * 512 + n];
    float Xi = fminf(fmaxf(rintf(__fmul_rn(__fmul_rn(__fadd_rn(w, 1.f), 0.5f), 255.f)),
                           0.f), 255.f);
    int xi = (int)Xi;
#pragma unroll
    for (int k = 0; k < 4; ++k) {
        int slc = (xi >> (2 * k)) & 3;
        float base = __fadd_rn(__fmul_rn((float)slc, 0.9f), 0.3f);
        float nf = __fadd_rn(1.f, __fmul_rn(0.05f, noise3[(f * 512 + n) * 4 + k]));
        g2t[n * 40 + k * 10 + f] = __fmul_rn(base, nf);
    }
}

// Layer-1 dummy column from transposed bit-planes: D = 0.3*popc(128 bits).
__global__ void dqpopT_kernel(const unsigned* __restrict__ xqbT, float* __restrict__ Dq)
{
    __shared__ float red[512];
    const int i = blockIdx.x / 7, s = blockIdx.x % 7;
    const int tid = threadIdx.x;
    float D[4];
    float mn = FLTMAX, mx = -FLTMAX;
#pragma unroll
    for (int u = 0; u < 4; ++u) {
        int b = tid + u * 256;
        int c = 0;
#pragma unroll
        for (int w = 0; w < 4; ++w)
            c += __popc(xqbT[(i * 28 + s * 4 + w) * 1024 + b]);
        D[u] = __fmul_rn((float)c, 0.3f);
        mn = fminf(mn, D[u]);
        mx = fmaxf(mx, D[u]);
    }
    red[tid] = mn; red[256 + tid] = mx;
    __syncthreads();
    for (int w = 128; w >= 1; w >>= 1) {
        if (tid < w) {
            red[tid] = fminf(red[tid], red[tid + w]);
            red[256 + tid] = fmaxf(red[256 + tid], red[256 + tid + w]);
        }
        __syncthreads();
    }
    mn = red[0]; mx = red[256];
    float step = __fmul_rn(__fsub_rn(mx, mn), 0.03125f);
    if (step <= 0.f) step = 1.f;
#pragma unroll
    for (int u = 0; u < 4; ++u) {
        int b = tid + u * 256;
        float idx = fminf(fmaxf(floorf(__fdiv_rn(__fsub_rn(D[u], mn), step)), 0.f), 31.f);
        Dq[(i * 7 + s) * 1024 + b] = __fadd_rn(__fmul_rn(idx, step), mn);
    }
}

// Layer-2 dummy column from xqb2 ([i][b][16w] layout).
__global__ void dqpop_kernel(const unsigned* __restrict__ xqb, float* __restrict__ Dq,
                             int S, int wpr)
{
    __shared__ float red[512];
    const int i = blockIdx.x / S, s = blockIdx.x % S;
    const int tid = threadIdx.x;
    float D[4];
    float mn = FLTMAX, mx = -FLTMAX;
#pragma unroll
    for (int u = 0; u < 4; ++u) {
        int b = tid + u * 256;
        uint4 w = *(const uint4*)&xqb[(i * 1024 + b) * wpr + s * 4];
        int c = __popc(w.x) + __popc(w.y) + __popc(w.z) + __popc(w.w);
        D[u] = __fmul_rn((float)c, 0.3f);
        mn = fminf(mn, D[u]);
        mx = fmaxf(mx, D[u]);
    }
    red[tid] = mn; red[256 + tid] = mx;
    __syncthreads();
    for (int w = 128; w >= 1; w >>= 1) {
        if (tid < w) {
            red[tid] = fminf(red[tid], red[tid + w]);
            red[256 + tid] = fmaxf(red[256 + tid], red[256 + tid + w]);
        }
        __syncthreads();
    }
    mn = red[0]; mx = red[256];
    float step = __fmul_rn(__fsub_rn(mx, mn), 0.03125f);
    if (step <= 0.f) step = 1.f;
#pragma unroll
    for (int u = 0; u < 4; ++u) {
        int b = tid + u * 256;
        float idx = fminf(fmaxf(floorf(__fdiv_rn(__fsub_rn(D[u], mn), step)), 0.f), 31.f);
        Dq[(i * S + s) * 1024 + b] = __fadd_rn(__fmul_rn(idx, step), mn);
    }
}

// ---------------------------------------------------------------------------
// Layer-1 persistent GEMM: 1024 blocks, distributed throttled grid barrier,
// tile-major contiguous Pidx stores.
// Pidx layout: tile = ((s*8+i)*16 + colgrp)*8 + btile; 16384 bytes per tile,
// within tile: byte = rowLocal*128 + colLocal.
// ---------------------------------------------------------------------------
#define BK 32
__global__ __launch_bounds__(256, 4) void mm1_kernel(
    const unsigned* __restrict__ xqbT, const float* __restrict__ g1t,
    unsigned char* __restrict__ Pidx, unsigned* stats, unsigned* bar)
{
    __shared__ __align__(16) float Bs[BK][132];
    __shared__ unsigned Abits[128];
    __shared__ float red[512];
    __shared__ __align__(16) unsigned stage[128 * 33];   // 128x128 uint8 tile, +1 word pad/row
    const int tid = threadIdx.x;
    const int r = blockIdx.x & 63;
    const int i = r >> 3;
    const int btile = r & 7;
    const int b0 = btile * 128;
    const int colgrp = blockIdx.x >> 6;             // 0..15
    const int colBase = colgrp * 128;               // [0, 2048)
    const int tx = tid & 15, ty = tid >> 4;
    const int aB = tid >> 5;          // 0..7  (B rows: u*8 + aB)
    const int eB = (tid & 31) << 2;   // 0..124
    const int k = colgrp >> 2;        // colBase>>9
    // store-phase mapping: lane l -> 8 rows x 8 chunks of 16B (1KB/wave-instr)
    const int wv = tid >> 6, ln = tid & 63;
    const int rsub = ln >> 3, chunk = ln & 7;

    for (int s = 0; s < 7; ++s) {
        // prefetch chunk 0  (xqbT layout: [i][w][b], w = s*4 + chunk)
        float4 pB[4];
        unsigned pAw = 0;
#pragma unroll
        for (int u = 0; u < 4; ++u)
            pB[u] = *(const float4*)&g1t[(s * 128 + u * 8 + aB) * 2048 + colBase + eB];
        if (tid < 128) pAw = xqbT[(i * 28 + s * 4) * 1024 + b0 + tid];

        float acc[8][8] = {};

        for (int ac = 0; ac < 4; ++ac) {
            __syncthreads();
#pragma unroll
            for (int u = 0; u < 4; ++u)
                *(float4*)&Bs[u * 8 + aB][eB] = pB[u];
            if (tid < 128) Abits[tid] = pAw;
            __syncthreads();

            if (ac < 3) {
                const int n0 = s * 128 + (ac + 1) * BK;
#pragma unroll
                for (int u = 0; u < 4; ++u)
                    pB[u] = *(const float4*)&g1t[(n0 + u * 8 + aB) * 2048 + colBase + eB];
                if (tid < 128) pAw = xqbT[(i * 28 + s * 4 + ac + 1) * 1024 + b0 + tid];
            }

            unsigned wrd[8];
#pragma unroll
            for (int u = 0; u < 4; ++u) {
                wrd[u]     = Abits[(ty << 2) + u];
                wrd[4 + u] = Abits[64 + (ty << 2) + u];
            }

#pragma unroll 4
            for (int a = 0; a < BK; ++a) {
                float br[8];
                *(float4*)&br[0] = *(const float4*)&Bs[a][(tx << 2)];
                *(float4*)&br[4] = *(const float4*)&Bs[a][64 + (tx << 2)];
#pragma unroll
                for (int u = 0; u < 8; ++u) {
                    float ab = (float)((wrd[u] >> a) & 1u);
#pragma unroll
                    for (int v = 0; v < 8; ++v)
                        acc[u][v] = fmaf(ab, br[v], acc[u][v]);
                }
            }
        }

        // block min/max -> global stats (uint order == float order for P >= 0)
        float mn = acc[0][0], mx = acc[0][0];
#pragma unroll
        for (int u = 0; u < 8; ++u)
#pragma unroll
            for (int v = 0; v < 8; ++v) { mn = fminf(mn, acc[u][v]); mx = fmaxf(mx, acc[u][v]); }
        red[tid] = mn; red[256 + tid] = mx;
        __syncthreads();
        for (int w = 128; w >= 1; w >>= 1) {
            if (tid < w) {
                red[tid] = fminf(red[tid], red[tid + w]);
                red[256 + tid] = fmaxf(red[256 + tid], red[256 + tid + w]);
            }
            __syncthreads();
        }
        const int slot = ((s * 8 + i) * 4 + k) * 2;
        if (tid == 0) {
            atomicMin(&stats[slot], __float_as_uint(red[0]));
            atomicMax(&stats[slot + 1], __float_as_uint(red[256]));
        }

        grid_barrier(bar, s, 1024u);   // plane stats complete device-wide

        // COHERENT read at the atomics' coherence point (relaxed: no
        // invalidation; the value only exists past L2, never cached).
        unsigned mnu = __hip_atomic_load(&stats[slot],     __ATOMIC_RELAXED,
                                         __HIP_MEMORY_SCOPE_AGENT);
        unsigned mxu = __hip_atomic_load(&stats[slot + 1], __ATOMIC_RELAXED,
                                         __HIP_MEMORY_SCOPE_AGENT);
        float qmn = __uint_as_float(mnu);
        float qmx = __uint_as_float(mxu);
        float step = __fmul_rn(__fsub_rn(qmx, qmn), 0.03125f);
        if (step <= 0.f) step = 1.f;

        // quantize in-register -> pack 4 indices/word -> LDS stage
#pragma unroll
        for (int uh = 0; uh < 2; ++uh)
#pragma unroll
            for (int u = 0; u < 4; ++u) {
                int rr = uh * 64 + (ty << 2) + u;
#pragma unroll
                for (int vh = 0; vh < 2; ++vh) {
                    float ix;
                    unsigned pack;
                    ix = fminf(fmaxf(floorf(__fdiv_rn(__fsub_rn(acc[uh * 4 + u][vh * 4 + 0], qmn), step)), 0.f), 31.f);
                    pack = (unsigned)(int)ix;
                    ix = fminf(fmaxf(floorf(__fdiv_rn(__fsub_rn(acc[uh * 4 + u][vh * 4 + 1], qmn), step)), 0.f), 31.f);
                    pack |= (unsigned)(int)ix << 8;
                    ix = fminf(fmaxf(floorf(__fdiv_rn(__fsub_rn(acc[uh * 4 + u][vh * 4 + 2], qmn), step)), 0.f), 31.f);
                    pack |= (unsigned)(int)ix << 16;
                    ix = fminf(fmaxf(floorf(__fdiv_rn(__fsub_rn(acc[uh * 4 + u][vh * 4 + 3], qmn), step)), 0.f), 31.f);
                    pack |= (unsigned)(int)ix << 24;
                    stage[rr * 33 + vh * 16 + tx] = pack;
                }
            }
        __syncthreads();

        // tile-major contiguous write: this block's 16KB tile, each wave
        // instruction writes 1KB contiguous (64 lanes x 16B, 8 rows).
        unsigned char* tbase = Pidx +
            ((size_t)(((s * 8 + i) * 16 + colgrp) * 8 + btile)) * 16384;
#pragma unroll
        for (int t = 0; t < 4; ++t) {
            int rr = t * 32 + wv * 8 + rsub;
            const unsigned* sp = &stage[rr * 33 + chunk * 4];
            uint4 v = make_uint4(sp[0], sp[1], sp[2], sp[3]);
            *(uint4*)&tbase[rr * 128 + chunk * 16] = v;
        }
        // stage is not rewritten until after the next grid_barrier (plenty
        // of intervening __syncthreads), so no extra sync needed here.
    }
}

// fold1: reconstruct pq = idx*step + mn (exact same fp32 ops as before) and
// run the full original chain: for s ascending { sum = i-outer/k-inner fmaf
// chain; acc += sum }, subtract dterm1, tanh -> xq2 codes, xqb2 bit-planes
// via ballot, sx2 row sum. Block per b, 512 threads.
// Pidx element (s,i,b,f,kk): tile = ((s*8+i)*16 + kk*4 + (f>>7))*8 + (b>>7);
// byte = tile*16384 + (b&127)*128 + (f&127).
__global__ void fold1_kernel(const unsigned char* __restrict__ Pidx,
                             const unsigned* __restrict__ stats,
                             const float* __restrict__ Dq1, const float* __restrict__ sx1,
                             float* __restrict__ xq2, unsigned* __restrict__ xqb2,
                             float* __restrict__ sx2)
{
    __shared__ float red[512];
    __shared__ float dt;
    __shared__ float2 st[224];
    int b = blockIdx.x;
    int f = threadIdx.x;                      // 0..511
    if (f < 224) {
        float mn = __uint_as_float(stats[f * 2]);
        float mx = __uint_as_float(stats[f * 2 + 1]);
        float step = __fmul_rn(__fsub_rn(mx, mn), 0.03125f);
        if (step <= 0.f) step = 1.f;
        st[f] = make_float2(mn, step);
    }
    if (f == 0) {
        float sd = 0.f;
        for (int i = 0; i < 8; ++i) {
            float sc = (float)(85 << i);
            for (int ss = 0; ss < 7; ++ss) sd = fmaf(Dq1[(i * 7 + ss) * 1024 + b], sc, sd);
        }
        dt = sd;
    }
    __syncthreads();
    const int fhi = f >> 7, fl = f & 127;
    // base for (btile, rowLocal, colLocal); per-(s,i,kk) add tilegrp*131072
    const unsigned char* pb = Pidx + (size_t)(b >> 7) * 16384
                                   + (size_t)(b & 127) * 128 + fl;
    float accR = 0.f;
    for (int s = 0; s < 7; ++s) {
        float sum = 0.f;
        for (int i = 0; i < 8; ++i) {
            const int si16 = (s * 8 + i) * 16;
#pragma unroll
            for (int kk = 0; kk < 4; ++kk) {
                float2 ms = st[((s * 8 + i) << 2) + kk];
                float ixv = (float)pb[(size_t)(si16 + kk * 4 + fhi) * 131072];
                float pq = __fadd_rn(__fmul_rn(ixv, ms.y), ms.x);
                sum = fmaf(pq, (float)(1 << (i + 2 * kk)), sum);
            }
        }
        accR = __fadd_rn(accR, sum);
    }
    float total = __fsub_rn(accR, dt);
    float acc = __fdiv_rn(total, 0.9f);
    float o = __fsub_rn(__fdiv_rn(__fmul_rn(2.f, acc), 65025.f), __fdiv_rn(sx1[b], 255.f));
    float h = tanhf(o);
    h = fminf(fmaxf(h, 0.f), 1.f);
    float code = rintf(__fmul_rn(h, 255.f));
    xq2[b * 512 + f] = code;
    int ci = (int)code;
    int lane = f & 63;
#pragma unroll
    for (int i = 0; i < 8; ++i) {
        unsigned long long m = __ballot((ci >> i) & 1);
        if ((lane & 31) == 0) {
            unsigned wv = (lane & 32) ? (unsigned)(m >> 32) : (unsigned)m;
            xqb2[(i * 1024 + b) * 16 + (f >> 5)] = wv;
        }
    }
    red[f] = code;
    __syncthreads();
    for (int w = 256; w >= 1; w >>= 1) {
        if (f < w) red[f] += red[f + w];
        __syncthreads();
    }
    if (f == 0) sx2[b] = red[0];
}

// Layer-2 matmul: thread per (s,b,f), 32 accumulators (i,k)
__global__ void mm2_kernel(const float* __restrict__ xq2, const float* __restrict__ g2t,
                           float* __restrict__ P2)
{
    int gid = blockIdx.x * 256 + threadIdx.x;  // 40960
    if (gid >= 40960) return;
    int f = gid % 10;
    int b = (gid / 10) & 1023;
    int s = gid / 10240;
    float acc[8][4] = {};
    for (int a = 0; a < 128; ++a) {
        int n = s * 128 + a;
        int xi = (int)xq2[b * 512 + n];
        float g0 = g2t[n * 40 + f];
        float gA = g2t[n * 40 + 10 + f];
        float gB = g2t[n * 40 + 20 + f];
        float gC = g2t[n * 40 + 30 + f];
#pragma unroll
        for (int i = 0; i < 8; ++i) {
            float bi = (float)((xi >> i) & 1);
            acc[i][0] = fmaf(bi, g0, acc[i][0]);
            acc[i][1] = fmaf(bi, gA, acc[i][1]);
            acc[i][2] = fmaf(bi, gB, acc[i][2]);
            acc[i][3] = fmaf(bi, gC, acc[i][3]);
        }
    }
#pragma unroll
    for (int i = 0; i < 8; ++i)
#pragma unroll
        for (int k = 0; k < 4; ++k)
            P2[(size_t)((s * 8 + i) * 4 + k) * 10240 + b * 10 + f] = acc[i][k];
}

__global__ void stat2_kernel(const float* __restrict__ P2, float2* __restrict__ stats2)
{
    __shared__ float red[512];
    int p = blockIdx.x;  // 128 planes
    int tid = threadIdx.x;
    float mn = FLTMAX, mx = -FLTMAX;
    for (int t = tid; t < 10240; t += 256) {
        float v = P2[(size_t)p * 10240 + t];
        mn = fminf(mn, v); mx = fmaxf(mx, v);
    }
    red[tid] = mn; red[256 + tid] = mx;
    __syncthreads();
    for (int w = 128; w >= 1; w >>= 1) {
        if (tid < w) {
            red[tid] = fminf(red[tid], red[tid + w]);
            red[256 + tid] = fmaxf(red[256 + tid], red[256 + tid + w]);
        }
        __syncthreads();
    }
    if (tid == 0) {
        float step = __fmul_rn(__fsub_rn(red[256], red[0]), 0.03125f);
        if (step <= 0.f) step = 1.f;
        stats2[p] = make_float2(red[0], step);
    }
}

// dterm2[b] computed inline per thread (exact i-outer/s-inner chain).
__global__ void out2_kernel(const float* __restrict__ P2, const float2* __restrict__ stats2,
                            const float* __restrict__ Dq2, const float* __restrict__ sx2,
                            float* __restrict__ out)
{
    int gid = blockIdx.x * 256 + threadIdx.x;  // 10240
    if (gid >= 10240) return;
    int b = gid / 10;
    float dt = 0.f;
    for (int i = 0; i < 8; ++i) {
        float sc = (float)(85 << i);
        for (int s = 0; s < 4; ++s) dt = fmaf(Dq2[(i * 4 + s) * 1024 + b], sc, dt);
    }
    float sum = 0.f;
    for (int s = 0; s < 4; ++s)
        for (int i = 0; i < 8; ++i)
#pragma unroll
            for (int k = 0; k < 4; ++k) {
                int p = (s * 8 + i) * 4 + k;
                float2 st = stats2[p];
                float val = P2[(size_t)p * 10240 + gid];
                float idx = fminf(fmaxf(floorf(__fdiv_rn(__fsub_rn(val, st.x), st.y)), 0.f), 31.f);
                float pq = __fadd_rn(__fmul_rn(idx, st.y), st.x);
                sum = fmaf(pq, (float)(1 << (i + 2 * k)), sum);
            }
    float total = __fsub_rn(sum, dt);
    float acc = __fdiv_rn(total, 0.9f);
    out[gid] = __fsub_rn(__fdiv_rn(__fmul_rn(2.f, acc), 65025.f), __fdiv_rn(sx2[b], 255.f));
}

extern "C" void kernel_launch(void* const* d_in, const int* in_sizes, int n_in,
                              void* d_out, int out_size, void* d_ws, size_t ws_size,
                              hipStream_t stream)
{
    const float* x      = (const float*)d_in[0];
    const float* w1     = (const float*)d_in[1];
    const float* w3     = (const float*)d_in[2];
    const float* noise1 = (const float*)d_in[3];
    const float* noise3 = (const float*)d_in[4];
    float* out = (float*)d_out;
    float* ws  = (float*)d_ws;

    // ws layout (float offsets)
    float*         g1t    = ws + 0;              // 896*2048
    float*         xq2    = ws + 1835008;        // 1024*512
    float*         P2     = ws + 2359296;        // 128*10240
    float*         g2t    = ws + 3670016;        // 512*40
    float*         Dq1    = ws + 3690496;        // 56*1024
    float*         Dq2    = ws + 3747840;        // 32*1024
    float*         sx1    = ws + 3780608;        // 1024
    float*         sx2    = ws + 3781632;        // 1024
    float2*        stats2 = (float2*)(ws + 3782656);    // 128 pairs
    unsigned*      stats1 = (unsigned*)(ws + 3782912);  // 224*2 words
    unsigned*      xqbT   = (unsigned*)(ws + 3783424);  // 8*28*1024 words
    unsigned*      xqb2   = (unsigned*)(ws + 4012800);  // 8*1024*16 words
    unsigned char* Pidx   = (unsigned char*)(ws + 4143872);  // 7168 tiles * 16KB
    unsigned*      bar    = (unsigned*)(ws + 33504256); // 1008 words (after Pidx)

    prep1_kernel<<<1024, 128, 0, stream>>>(x, sx1, xqbT, stats1, bar);
    prepg1t_kernel<<<dim3(28, 16), 256, 0, stream>>>(w1, noise1, g1t);
    dqpopT_kernel<<<56, 256, 0, stream>>>(xqbT, Dq1);

    mm1_kernel<<<1024, 256, 0, stream>>>(xqbT, g1t, Pidx, stats1, bar);

    fold1_kernel<<<1024, 512, 0, stream>>>(Pidx, stats1, Dq1, sx1, xq2, xqb2, sx2);
    prepg2_kernel<<<20, 256, 0, stream>>>(w3, noise3, g2t);
    dqpop_kernel<<<32, 256, 0, stream>>>(xqb2, Dq2, 4, 16);
    mm2_kernel<<<160, 256, 0, stream>>>(xq2, g2t, P2);
    stat2_kernel<<<128, 256, 0, stream>>>(P2, stats2);
    out2_kernel<<<40, 256, 0, stream>>>(P2, stats2, Dq2, sx2, out);
}

// Round 8
// 634.230 us; speedup vs baseline: 1.0513x; 1.0513x over previous
//
#include <hip/hip_runtime.h>

#define FLTMAX 3.402823466e+38f

// ---------------------------------------------------------------------------
// Geometry:
//   Layer1: B=1024, N=784, Np=896, S=7, F=512, I=8, K=4
//   Layer2: B=1024, N=512, Np=512, S=4, F=10,  I=8, K=4
// Layer-1: persistent-grid kernel, 512 blocks at __launch_bounds__(256,2)
// (= exactly 2 blocks/CU x 256 CU co-resident; 256-VGPR/thread budget).
// Each block owns TWO adjacent (i,btile) 128x128 tiles of one col-group:
// acc[2][8][8] = 128 regs/thread, comfortably under 256 -> NO SPILL.
//
// R7 post-mortem: write amplification (~4x Pidx, invariant across 4 store
// layouts) + VALU inflation (387us busy vs ~230us of source work) + fetch
// excess ~100MB = REGISTER SPILL of acc across the barrier/quant phase at
// the 128-reg budget of (256,4). R0's clean kernel (no quant phase, acc
// dies at store) showed none. Fix: (256,2) -> 256-reg budget; grid 512;
// 2 tiles/block (B-tile LDS now shared by both -> halved g1t re-reads).
//
// Barrier (R6, kept): arrivals on 8 counters in separate 64B lines; block 0
// detects and writes a release flag; s_sleep throttling; vmcnt(0) before
// arrival orders the stats atomics; stats read via RELAXED AGENT atomic
// loads (coherence point past the non-coherent per-XCD L2); no fences
// (R3: fences = L2 flush storms).
// Pidx layout (R7, kept): tile-major, tile = ((s*8+i)*16+colgrp)*8+btile,
// 16KB contiguous per tile.
// ---------------------------------------------------------------------------

// bar layout (unsigned words): plane s: 8 arrival counters at [s*128 + j*16]
// (64B apart); release flag at [896 + s*16]. Total 1008 words.
__device__ __forceinline__ void grid_barrier(unsigned* bar, int s, unsigned nblk)
{
    __syncthreads();
    if (threadIdx.x == 0) {
        unsigned* ctr = bar + s * 128;
        unsigned* rel = bar + 896 + s * 16;
        // drain this wave's outstanding VMEM (incl. the stats atomics) so
        // they are complete at the coherence point before we signal.
        asm volatile("s_waitcnt vmcnt(0)" ::: "memory");
        __hip_atomic_fetch_add(&ctr[(blockIdx.x & 7) << 4], 1u,
                               __ATOMIC_RELAXED, __HIP_MEMORY_SCOPE_AGENT);
        if (blockIdx.x == 0) {
            for (int it = 0; it < (1 << 20); ++it) {
                unsigned tot = 0;
#pragma unroll
                for (int j = 0; j < 8; ++j)
                    tot += __hip_atomic_load(&ctr[j << 4], __ATOMIC_RELAXED,
                                             __HIP_MEMORY_SCOPE_AGENT);
                if (tot >= nblk) break;
                __builtin_amdgcn_s_sleep(8);
            }
            __hip_atomic_store(rel, 1u, __ATOMIC_RELAXED, __HIP_MEMORY_SCOPE_AGENT);
        } else {
            for (int it = 0; it < (1 << 20); ++it) {
                if (__hip_atomic_load(rel, __ATOMIC_RELAXED,
                                      __HIP_MEMORY_SCOPE_AGENT) != 0u)
                    break;
                __builtin_amdgcn_s_sleep(16);
            }
        }
    }
    __syncthreads();
}

// Fused: xq codes (row in LDS) -> sx1 row sum + bit-packed planes xqbT[i][w][b].
// Also initializes stats1 + barrier region.
__global__ void prep1_kernel(const float* __restrict__ x, float* __restrict__ sx1,
                             unsigned* __restrict__ xqbT, unsigned* __restrict__ stats1,
                             unsigned* __restrict__ bar)
{
    __shared__ float xr[896];
    __shared__ float red[128];
    int b = blockIdx.x;
    if (b == 0) {
        for (int t = threadIdx.x; t < 224; t += 128) {
            stats1[t * 2] = 0x7F7FFFFFu; stats1[t * 2 + 1] = 0u;
        }
        for (int t = threadIdx.x; t < 1008; t += 128) bar[t] = 0u;
    }
    float psum = 0.f;
    for (int n = threadIdx.x; n < 896; n += 128) {
        float v = 0.f;
        if (n < 784) {
            float xv = x[b * 784 + n];
            xv = fminf(fmaxf(xv, 0.f), 1.f);
            v = rintf(__fmul_rn(xv, 255.f));
        }
        xr[n] = v;
        psum += v;  // integer-valued, exact in any order
    }
    red[threadIdx.x] = psum;
    __syncthreads();
    for (int w = 64; w >= 1; w >>= 1) {
        if (threadIdx.x < w) red[threadIdx.x] += red[threadIdx.x + w];
        __syncthreads();
    }
    if (threadIdx.x == 0) sx1[b] = red[0];
    if (threadIdx.x < 28) {
        int w = threadIdx.x;
        unsigned words[8] = {0, 0, 0, 0, 0, 0, 0, 0};
#pragma unroll 8
        for (int n = 0; n < 32; ++n) {
            int v = (int)xr[w * 32 + n];
#pragma unroll
            for (int i = 0; i < 8; ++i) words[i] |= ((unsigned)((v >> i) & 1)) << n;
        }
#pragma unroll
        for (int i = 0; i < 8; ++i) xqbT[(i * 28 + w) * 1024 + b] = words[i];
    }
}

// Fused conductance-prep + transpose: writes g1t[n][k*512+f] directly.
__global__ void prepg1t_kernel(const float* __restrict__ w1, const float* __restrict__ noise1,
                               float* __restrict__ g1t)
{
    __shared__ float t[4][32][33];
    const int n0 = blockIdx.x * 32, f0 = blockIdx.y * 32;
    const int tid = threadIdx.x;
    {
        int n = tid & 31, fi = tid >> 5;
#pragma unroll
        for (int p = 0; p < 4; ++p) {
            int f = p * 8 + fi;
            int gn = n0 + n, gf = f0 + f;
            float gv[4] = {0.f, 0.f, 0.f, 0.f};
            if (gn < 784) {
                float w = w1[gf * 784 + gn];
                float Xi = fminf(fmaxf(rintf(__fmul_rn(__fmul_rn(__fadd_rn(w, 1.f), 0.5f), 255.f)),
                                       0.f), 255.f);
                int xi = (int)Xi;
                float4 nz = *(const float4*)&noise1[(gf * 896 + gn) * 4];
                float nzv[4] = {nz.x, nz.y, nz.z, nz.w};
#pragma unroll
                for (int k = 0; k < 4; ++k) {
                    int slc = (xi >> (2 * k)) & 3;
                    float base = __fadd_rn(__fmul_rn((float)slc, 0.9f), 0.3f);
                    float nf = __fadd_rn(1.f, __fmul_rn(0.05f, nzv[k]));
                    gv[k] = __fmul_rn(base, nf);
                }
            }
#pragma unroll
            for (int k = 0; k < 4; ++k) t[k][n][f] = gv[k];
        }
    }
    __syncthreads();
    {
        int f = tid & 31, nn = tid >> 5;
#pragma unroll
        for (int p = 0; p < 4; ++p) {
            int n = p * 8 + nn;
#pragma unroll
            for (int k = 0; k < 4; ++k)
                g1t[(n0 + n) * 2048 + k * 512 + f0 + f] = t[k][n][f];
        }
    }
}

// g2t[n][k][f] layout for layer-2 matmul
__global__ void prepg2_kernel(const float* __restrict__ w3, const float* __restrict__ noise3,
                              float* __restrict__ g2t)
{
    int gid = blockIdx.x * 256 + threadIdx.x;
    if (gid >= 10 * 512) return;
    int f = gid / 512, n = gid % 512;
    float w = w3[f * 512 + n];
    float Xi = fminf(fmaxf(rintf(__fmul_rn(__fmul_rn(__fadd_rn(w, 1.f), 0.5f), 255.f)),
                           0.f), 255.f);
    int xi = (int)Xi;
#pragma unroll
    for (int k = 0; k < 4; ++k) {
        int slc = (xi >> (2 * k)) & 3;
        float base = __fadd_rn(__fmul_rn((float)slc, 0.9f), 0.3f);
        float nf = __fadd_rn(1.f, __fmul_rn(0.05f, noise3[(f * 512 + n) * 4 + k]));
        g2t[n * 40 + k * 10 + f] = __fmul_rn(base, nf);
    }
}

// Layer-1 dummy column from transposed bit-planes: D = 0.3*popc(128 bits).
__global__ void dqpopT_kernel(const unsigned* __restrict__ xqbT, float* __restrict__ Dq)
{
    __shared__ float red[512];
    const int i = blockIdx.x / 7, s = blockIdx.x % 7;
    const int tid = threadIdx.x;
    float D[4];
    float mn = FLTMAX, mx = -FLTMAX;
#pragma unroll
    for (int u = 0; u < 4; ++u) {
        int b = tid + u * 256;
        int c = 0;
#pragma unroll
        for (int w = 0; w < 4; ++w)
            c += __popc(xqbT[(i * 28 + s * 4 + w) * 1024 + b]);
        D[u] = __fmul_rn((float)c, 0.3f);
        mn = fminf(mn, D[u]);
        mx = fmaxf(mx, D[u]);
    }
    red[tid] = mn; red[256 + tid] = mx;
    __syncthreads();
    for (int w = 128; w >= 1; w >>= 1) {
        if (tid < w) {
            red[tid] = fminf(red[tid], red[tid + w]);
            red[256 + tid] = fmaxf(red[256 + tid], red[256 + tid + w]);
        }
        __syncthreads();
    }
    mn = red[0]; mx = red[256];
    float step = __fmul_rn(__fsub_rn(mx, mn), 0.03125f);
    if (step <= 0.f) step = 1.f;
#pragma unroll
    for (int u = 0; u < 4; ++u) {
        int b = tid + u * 256;
        float idx = fminf(fmaxf(floorf(__fdiv_rn(__fsub_rn(D[u], mn), step)), 0.f), 31.f);
        Dq[(i * 7 + s) * 1024 + b] = __fadd_rn(__fmul_rn(idx, step), mn);
    }
}

// Layer-2 dummy column from xqb2 ([i][b][16w] layout).
__global__ void dqpop_kernel(const unsigned* __restrict__ xqb, float* __restrict__ Dq,
                             int S, int wpr)
{
    __shared__ float red[512];
    const int i = blockIdx.x / S, s = blockIdx.x % S;
    const int tid = threadIdx.x;
    float D[4];
    float mn = FLTMAX, mx = -FLTMAX;
#pragma unroll
    for (int u = 0; u < 4; ++u) {
        int b = tid + u * 256;
        uint4 w = *(const uint4*)&xqb[(i * 1024 + b) * wpr + s * 4];
        int c = __popc(w.x) + __popc(w.y) + __popc(w.z) + __popc(w.w);
        D[u] = __fmul_rn((float)c, 0.3f);
        mn = fminf(mn, D[u]);
        mx = fmaxf(mx, D[u]);
    }
    red[tid] = mn; red[256 + tid] = mx;
    __syncthreads();
    for (int w = 128; w >= 1; w >>= 1) {
        if (tid < w) {
            red[tid] = fminf(red[tid], red[tid + w]);
            red[256 + tid] = fmaxf(red[256 + tid], red[256 + tid + w]);
        }
        __syncthreads();
    }
    mn = red[0]; mx = red[256];
    float step = __fmul_rn(__fsub_rn(mx, mn), 0.03125f);
    if (step <= 0.f) step = 1.f;
#pragma unroll
    for (int u = 0; u < 4; ++u) {
        int b = tid + u * 256;
        float idx = fminf(fmaxf(floorf(__fdiv_rn(__fsub_rn(D[u], mn), step)), 0.f), 31.f);
        Dq[(i * S + s) * 1024 + b] = __fadd_rn(__fmul_rn(idx, step), mn);
    }
}

// ---------------------------------------------------------------------------
// Layer-1 persistent GEMM: 512 blocks (2/CU at launch_bounds(256,2)), each
// computing TWO (i,btile) tiles of one col-group per plane; acc[2][8][8]
// lives in registers (256-reg budget, no spill). Distributed throttled grid
// barrier; tile-major contiguous Pidx stores.
// ---------------------------------------------------------------------------
#define BK 32
__global__ __launch_bounds__(256, 2) void mm1_kernel(
    const unsigned* __restrict__ xqbT, const float* __restrict__ g1t,
    unsigned char* __restrict__ Pidx, unsigned* stats, unsigned* bar)
{
    __shared__ __align__(16) float Bs[BK][132];
    __shared__ unsigned Abits[256];
    __shared__ float red[512];
    __shared__ __align__(16) unsigned stage[2][128 * 33];
    const int tid = threadIdx.x;
    const int pair = blockIdx.x & 31;        // 0..31 -> r = pair*2, pair*2+1
    const int i = pair >> 2;                 // 0..7
    const int bp = (pair & 3) * 256;         // row base of the btile PAIR
    const int btile0 = (pair * 2) & 7;       // even btile of the pair
    const int colgrp = blockIdx.x >> 5;      // 0..15
    const int colBase = colgrp * 128;
    const int tx = tid & 15, ty = tid >> 4;
    const int aB = tid >> 5;          // 0..7  (B rows: u*8 + aB)
    const int eB = (tid & 31) << 2;   // 0..124
    const int k = colgrp >> 2;
    // store-phase mapping: lane l -> 8 rows x 8 chunks of 16B (1KB/wave-instr)
    const int wv = tid >> 6, ln = tid & 63;
    const int rsub = ln >> 3, chunk = ln & 7;

    for (int s = 0; s < 7; ++s) {
        // prefetch chunk 0  (xqbT layout: [i][w][b], w = s*4 + chunk)
        float4 pB[4];
#pragma unroll
        for (int u = 0; u < 4; ++u)
            pB[u] = *(const float4*)&g1t[(s * 128 + u * 8 + aB) * 2048 + colBase + eB];
        unsigned pAw = xqbT[(i * 28 + s * 4) * 1024 + bp + tid];

        float acc[2][8][8] = {};

        for (int ac = 0; ac < 4; ++ac) {
            __syncthreads();
#pragma unroll
            for (int u = 0; u < 4; ++u)
                *(float4*)&Bs[u * 8 + aB][eB] = pB[u];
            Abits[tid] = pAw;
            __syncthreads();

            if (ac < 3) {
                const int n0 = s * 128 + (ac + 1) * BK;
#pragma unroll
                for (int u = 0; u < 4; ++u)
                    pB[u] = *(const float4*)&g1t[(n0 + u * 8 + aB) * 2048 + colBase + eB];
                pAw = xqbT[(i * 28 + s * 4 + ac + 1) * 1024 + bp + tid];
            }

            unsigned wrd[2][8];
#pragma unroll
            for (int q = 0; q < 2; ++q)
#pragma unroll
                for (int u = 0; u < 4; ++u) {
                    wrd[q][u]     = Abits[q * 128 + (ty << 2) + u];
                    wrd[q][4 + u] = Abits[q * 128 + 64 + (ty << 2) + u];
                }

#pragma unroll 4
            for (int a = 0; a < BK; ++a) {
                float br[8];
                *(float4*)&br[0] = *(const float4*)&Bs[a][(tx << 2)];
                *(float4*)&br[4] = *(const float4*)&Bs[a][64 + (tx << 2)];
#pragma unroll
                for (int q = 0; q < 2; ++q)
#pragma unroll
                    for (int u = 0; u < 8; ++u) {
                        float ab = (float)((wrd[q][u] >> a) & 1u);
#pragma unroll
                        for (int v = 0; v < 8; ++v)
                            acc[q][u][v] = fmaf(ab, br[v], acc[q][u][v]);
                    }
            }
        }

        // block min/max over BOTH tiles (same stats slot: same s,i,k)
        float mn = acc[0][0][0], mx = acc[0][0][0];
#pragma unroll
        for (int q = 0; q < 2; ++q)
#pragma unroll
            for (int u = 0; u < 8; ++u)
#pragma unroll
                for (int v = 0; v < 8; ++v) {
                    mn = fminf(mn, acc[q][u][v]); mx = fmaxf(mx, acc[q][u][v]);
                }
        red[tid] = mn; red[256 + tid] = mx;
        __syncthreads();
        for (int w = 128; w >= 1; w >>= 1) {
            if (tid < w) {
                red[tid] = fminf(red[tid], red[tid + w]);
                red[256 + tid] = fmaxf(red[256 + tid], red[256 + tid + w]);
            }
            __syncthreads();
        }
        const int slot = ((s * 8 + i) * 4 + k) * 2;
        if (tid == 0) {
            atomicMin(&stats[slot], __float_as_uint(red[0]));
            atomicMax(&stats[slot + 1], __float_as_uint(red[256]));
        }

        grid_barrier(bar, s, 512u);   // plane stats complete device-wide

        // COHERENT read at the atomics' coherence point.
        unsigned mnu = __hip_atomic_load(&stats[slot],     __ATOMIC_RELAXED,
                                         __HIP_MEMORY_SCOPE_AGENT);
        unsigned mxu = __hip_atomic_load(&stats[slot + 1], __ATOMIC_RELAXED,
                                         __HIP_MEMORY_SCOPE_AGENT);
        float qmn = __uint_as_float(mnu);
        float qmx = __uint_as_float(mxu);
        float step = __fmul_rn(__fsub_rn(qmx, qmn), 0.03125f);
        if (step <= 0.f) step = 1.f;

        // quantize in-register -> pack 4 indices/word -> LDS stage (per tile)
#pragma unroll
        for (int q = 0; q < 2; ++q)
#pragma unroll
            for (int uh = 0; uh < 2; ++uh)
#pragma unroll
                for (int u = 0; u < 4; ++u) {
                    int rr = uh * 64 + (ty << 2) + u;
#pragma unroll
                    for (int vh = 0; vh < 2; ++vh) {
                        float ix;
                        unsigned pack;
                        ix = fminf(fmaxf(floorf(__fdiv_rn(__fsub_rn(acc[q][uh * 4 + u][vh * 4 + 0], qmn), step)), 0.f), 31.f);
                        pack = (unsigned)(int)ix;
                        ix = fminf(fmaxf(floorf(__fdiv_rn(__fsub_rn(acc[q][uh * 4 + u][vh * 4 + 1], qmn), step)), 0.f), 31.f);
                        pack |= (unsigned)(int)ix << 8;
                        ix = fminf(fmaxf(floorf(__fdiv_rn(__fsub_rn(acc[q][uh * 4 + u][vh * 4 + 2], qmn), step)), 0.f), 31.f);
                        pack |= (unsigned)(int)ix << 16;
                        ix = fminf(fmaxf(floorf(__fdiv_rn(__fsub_rn(acc[q][uh * 4 + u][vh * 4 + 3], qmn), step)), 0.f), 31.f);
                        pack |= (unsigned)(int)ix << 24;
                        stage[q][rr * 33 + vh * 16 + tx] = pack;
                    }
                }
        __syncthreads();

        // tile-major contiguous write: 2 private 16KB tiles, each wave
        // instruction writes 1KB contiguous.
#pragma unroll
        for (int q = 0; q < 2; ++q) {
            unsigned char* tbase = Pidx +
                ((size_t)(((s * 8 + i) * 16 + colgrp) * 8 + btile0 + q)) * 16384;
#pragma unroll
            for (int t = 0; t < 4; ++t) {
                int rr = t * 32 + wv * 8 + rsub;
                const unsigned* sp = &stage[q][rr * 33 + chunk * 4];
                uint4 v = make_uint4(sp[0], sp[1], sp[2], sp[3]);
                *(uint4*)&tbase[rr * 128 + chunk * 16] = v;
            }
        }
        // stage not rewritten until after the next grid_barrier.
    }
}

// fold1: reconstruct pq = idx*step + mn (exact same fp32 ops as before) and
// run the full original chain. Block per b, 512 threads.
// Pidx element (s,i,b,f,kk): tile = ((s*8+i)*16 + kk*4 + (f>>7))*8 + (b>>7);
// byte = tile*16384 + (b&127)*128 + (f&127).
__global__ void fold1_kernel(const unsigned char* __restrict__ Pidx,
                             const unsigned* __restrict__ stats,
                             const float* __restrict__ Dq1, const float* __restrict__ sx1,
                             float* __restrict__ xq2, unsigned* __restrict__ xqb2,
                             float* __restrict__ sx2)
{
    __shared__ float red[512];
    __shared__ float dt;
    __shared__ float2 st[224];
    int b = blockIdx.x;
    int f = threadIdx.x;                      // 0..511
    if (f < 224) {
        float mn = __uint_as_float(stats[f * 2]);
        float mx = __uint_as_float(stats[f * 2 + 1]);
        float step = __fmul_rn(__fsub_rn(mx, mn), 0.03125f);
        if (step <= 0.f) step = 1.f;
        st[f] = make_float2(mn, step);
    }
    if (f == 0) {
        float sd = 0.f;
        for (int i = 0; i < 8; ++i) {
            float sc = (float)(85 << i);
            for (int ss = 0; ss < 7; ++ss) sd = fmaf(Dq1[(i * 7 + ss) * 1024 + b], sc, sd);
        }
        dt = sd;
    }
    __syncthreads();
    const int fhi = f >> 7, fl = f & 127;
    const unsigned char* pb = Pidx + (size_t)(b >> 7) * 16384
                                   + (size_t)(b & 127) * 128 + fl;
    float accR = 0.f;
    for (int s = 0; s < 7; ++s) {
        float sum = 0.f;
        for (int i = 0; i < 8; ++i) {
            const int si16 = (s * 8 + i) * 16;
#pragma unroll
            for (int kk = 0; kk < 4; ++kk) {
                float2 ms = st[((s * 8 + i) << 2) + kk];
                float ixv = (float)pb[(size_t)(si16 + kk * 4 + fhi) * 131072];
                float pq = __fadd_rn(__fmul_rn(ixv, ms.y), ms.x);
                sum = fmaf(pq, (float)(1 << (i + 2 * kk)), sum);
            }
        }
        accR = __fadd_rn(accR, sum);
    }
    float total = __fsub_rn(accR, dt);
    float acc = __fdiv_rn(total, 0.9f);
    float o = __fsub_rn(__fdiv_rn(__fmul_rn(2.f, acc), 65025.f), __fdiv_rn(sx1[b], 255.f));
    float h = tanhf(o);
    h = fminf(fmaxf(h, 0.f), 1.f);
    float code = rintf(__fmul_rn(h, 255.f));
    xq2[b * 512 + f] = code;
    int ci = (int)code;
    int lane = f & 63;
#pragma unroll
    for (int i = 0; i < 8; ++i) {
        unsigned long long m = __ballot((ci >> i) & 1);
        if ((lane & 31) == 0) {
            unsigned wv = (lane & 32) ? (unsigned)(m >> 32) : (unsigned)m;
            xqb2[(i * 1024 + b) * 16 + (f >> 5)] = wv;
        }
    }
    red[f] = code;
    __syncthreads();
    for (int w = 256; w >= 1; w >>= 1) {
        if (f < w) red[f] += red[f + w];
        __syncthreads();
    }
    if (f == 0) sx2[b] = red[0];
}

// Layer-2 matmul: thread per (s,b,f), 32 accumulators (i,k)
__global__ void mm2_kernel(const float* __restrict__ xq2, const float* __restrict__ g2t,
                           float* __restrict__ P2)
{
    int gid = blockIdx.x * 256 + threadIdx.x;  // 40960
    if (gid >= 40960) return;
    int f = gid % 10;
    int b = (gid / 10) & 1023;
    int s = gid / 10240;
    float acc[8][4] = {};
    for (int a = 0; a < 128; ++a) {
        int n = s * 128 + a;
        int xi = (int)xq2[b * 512 + n];
        float g0 = g2t[n * 40 + f];
        float gA = g2t[n * 40 + 10 + f];
        float gB = g2t[n * 40 + 20 + f];
        float gC = g2t[n * 40 + 30 + f];
#pragma unroll
        for (int i = 0; i < 8; ++i) {
            float bi = (float)((xi >> i) & 1);
            acc[i][0] = fmaf(bi, g0, acc[i][0]);
            acc[i][1] = fmaf(bi, gA, acc[i][1]);
            acc[i][2] = fmaf(bi, gB, acc[i][2]);
            acc[i][3] = fmaf(bi, gC, acc[i][3]);
        }
    }
#pragma unroll
    for (int i = 0; i < 8; ++i)
#pragma unroll
        for (int k = 0; k < 4; ++k)
            P2[(size_t)((s * 8 + i) * 4 + k) * 10240 + b * 10 + f] = acc[i][k];
}

__global__ void stat2_kernel(const float* __restrict__ P2, float2* __restrict__ stats2)
{
    __shared__ float red[512];
    int p = blockIdx.x;  // 128 planes
    int tid = threadIdx.x;
    float mn = FLTMAX, mx = -FLTMAX;
    for (int t = tid; t < 10240; t += 256) {
        float v = P2[(size_t)p * 10240 + t];
        mn = fminf(mn, v); mx = fmaxf(mx, v);
    }
    red[tid] = mn; red[256 + tid] = mx;
    __syncthreads();
    for (int w = 128; w >= 1; w >>= 1) {
        if (tid < w) {
            red[tid] = fminf(red[tid], red[tid + w]);
            red[256 + tid] = fmaxf(red[256 + tid], red[256 + tid + w]);
        }
        __syncthreads();
    }
    if (tid == 0) {
        float step = __fmul_rn(__fsub_rn(red[256], red[0]), 0.03125f);
        if (step <= 0.f) step = 1.f;
        stats2[p] = make_float2(red[0], step);
    }
}

// dterm2[b] computed inline per thread (exact i-outer/s-inner chain).
__global__ void out2_kernel(const float* __restrict__ P2, const float2* __restrict__ stats2,
                            const float* __restrict__ Dq2, const float* __restrict__ sx2,
                            float* __restrict__ out)
{
    int gid = blockIdx.x * 256 + threadIdx.x;  // 10240
    if (gid >= 10240) return;
    int b = gid / 10;
    float dt = 0.f;
    for (int i = 0; i < 8; ++i) {
        float sc = (float)(85 << i);
        for (int s = 0; s < 4; ++s) dt = fmaf(Dq2[(i * 4 + s) * 1024 + b], sc, dt);
    }
    float sum = 0.f;
    for (int s = 0; s < 4; ++s)
        for (int i = 0; i < 8; ++i)
#pragma unroll
            for (int k = 0; k < 4; ++k) {
                int p = (s * 8 + i) * 4 + k;
                float2 st = stats2[p];
                float val = P2[(size_t)p * 10240 + gid];
                float idx = fminf(fmaxf(floorf(__fdiv_rn(__fsub_rn(val, st.x), st.y)), 0.f), 31.f);
                float pq = __fadd_rn(__fmul_rn(idx, st.y), st.x);
                sum = fmaf(pq, (float)(1 << (i + 2 * k)), sum);
            }
    float total = __fsub_rn(sum, dt);
    float acc = __fdiv_rn(total, 0.9f);
    out[gid] = __fsub_rn(__fdiv_rn(__fmul_rn(2.f, acc), 65025.f), __fdiv_rn(sx2[b], 255.f));
}

extern "C" void kernel_launch(void* const* d_in, const int* in_sizes, int n_in,
                              void* d_out, int out_size, void* d_ws, size_t ws_size,
                              hipStream_t stream)
{
    const float* x      = (const float*)d_in[0];
    const float* w1     = (const float*)d_in[1];
    const float* w3     = (const float*)d_in[2];
    const float* noise1 = (const float*)d_in[3];
    const float* noise3 = (const float*)d_in[4];
    float* out = (float*)d_out;
    float* ws  = (float*)d_ws;

    // ws layout (float offsets)
    float*         g1t    = ws + 0;              // 896*2048
    float*         xq2    = ws + 1835008;        // 1024*512
    float*         P2     = ws + 2359296;        // 128*10240
    float*         g2t    = ws + 3670016;        // 512*40
    float*         Dq1    = ws + 3690496;        // 56*1024
    float*         Dq2    = ws + 3747840;        // 32*1024
    float*         sx1    = ws + 3780608;        // 1024
    float*         sx2    = ws + 3781632;        // 1024
    float2*        stats2 = (float2*)(ws + 3782656);    // 128 pairs
    unsigned*      stats1 = (unsigned*)(ws + 3782912);  // 224*2 words
    unsigned*      xqbT   = (unsigned*)(ws + 3783424);  // 8*28*1024 words
    unsigned*      xqb2   = (unsigned*)(ws + 4012800);  // 8*1024*16 words
    unsigned char* Pidx   = (unsigned char*)(ws + 4143872);  // 7168 tiles * 16KB
    unsigned*      bar    = (unsigned*)(ws + 33504256); // 1008 words (after Pidx)

    prep1_kernel<<<1024, 128, 0, stream>>>(x, sx1, xqbT, stats1, bar);
    prepg1t_kernel<<<dim3(28, 16), 256, 0, stream>>>(w1, noise1, g1t);
    dqpopT_kernel<<<56, 256, 0, stream>>>(xqbT, Dq1);

    mm1_kernel<<<512, 256, 0, stream>>>(xqbT, g1t, Pidx, stats1, bar);

    fold1_kernel<<<1024, 512, 0, stream>>>(Pidx, stats1, Dq1, sx1, xq2, xqb2, sx2);
    prepg2_kernel<<<20, 256, 0, stream>>>(w3, noise3, g2t);
    dqpop_kernel<<<32, 256, 0, stream>>>(xqb2, Dq2, 4, 16);
    mm2_kernel<<<160, 256, 0, stream>>>(xq2, g2t, P2);
    stat2_kernel<<<128, 256, 0, stream>>>(P2, stats2);
    out2_kernel<<<40, 256, 0, stream>>>(P2, stats2, Dq2, sx2, out);
}

// Round 9
// 624.647 us; speedup vs baseline: 1.0674x; 1.0153x over previous
//
#include <hip/hip_runtime.h>

#define FLTMAX 3.402823466e+38f

typedef float f32x2 __attribute__((ext_vector_type(2)));

// ---------------------------------------------------------------------------
// Geometry:
//   Layer1: B=1024, N=784, Np=896, S=7, F=512, I=8, K=4
//   Layer2: B=1024, N=512, Np=512, S=4, F=10,  I=8, K=4
// Layer-1: persistent-grid kernel, 512 blocks at __launch_bounds__(256,2)
// (2 blocks/CU co-resident, 256-reg budget -> no spill, R8-verified:
// WRITE 463->180MB, FETCH 150->33MB).
//
// R8 post-mortem: mm1 now VALU-issue + stall bound (VALUBusy 78%, occupancy
// 2 waves/SIMD). Two fixes this round:
//  1) PER-SLOT sync: stats slot (s,i,k) depends on only 16 blocks
//     (4 bp-groups x 4 colgrps) — global 512-block barrier made everyone
//     wait on the global straggler 7x. 224 slot counters (64B apart),
//     target 16; blocks desync and the 2 blocks/CU interleave phases.
//  2) Packed FP32: acc as float2 + __builtin_elementwise_fma (bit-exact
//     per-component IEEE FMA) -> v_pk_fma_f32 (2 FMA/instr) where the
//     backend allows; plain 2x fmaf otherwise (no regression).
//
// Ordering chain (R5-R8, passed): tid0 issues device-scope atomicMin/Max
// on stats; s_waitcnt vmcnt(0) drains them to the coherence point; THEN
// arrival fetch_add. Waiters spin on the slot counter (RELAXED AGENT) and
// read stats with RELAXED AGENT loads — both at the coherence point past
// the non-coherent per-XCD L2. No fences (R3: fences = L2 flush storms).
// Pidx layout (R7): tile-major, tile = ((s*8+i)*16+colgrp)*8+btile, 16KB
// contiguous per tile; LDS-staged 16B stores.
// ---------------------------------------------------------------------------

// slotbar: 224 counters, one per (s*8+i)*4+k, 64B apart (16 words).
__device__ __forceinline__ void slot_barrier(unsigned* ctr, unsigned target)
{
    __syncthreads();
    if (threadIdx.x == 0) {
        // drain this wave's outstanding VMEM (incl. the stats atomics) so
        // they are complete at the coherence point before we signal.
        asm volatile("s_waitcnt vmcnt(0)" ::: "memory");
        __hip_atomic_fetch_add(ctr, 1u, __ATOMIC_RELAXED, __HIP_MEMORY_SCOPE_AGENT);
        // bounded spin (fails visibly, never hangs): healthy wait << 50us
        for (int it = 0; it < (1 << 22); ++it) {
            if (__hip_atomic_load(ctr, __ATOMIC_RELAXED, __HIP_MEMORY_SCOPE_AGENT) >= target)
                break;
            __builtin_amdgcn_s_sleep(2);
        }
    }
    __syncthreads();
}

// Fused: xq codes (row in LDS) -> sx1 row sum + bit-packed planes xqbT[i][w][b].
// Also initializes stats1 + slot-barrier counters.
__global__ void prep1_kernel(const float* __restrict__ x, float* __restrict__ sx1,
                             unsigned* __restrict__ xqbT, unsigned* __restrict__ stats1,
                             unsigned* __restrict__ bar)
{
    __shared__ float xr[896];
    __shared__ float red[128];
    int b = blockIdx.x;
    if (b == 0) {
        for (int t = threadIdx.x; t < 224; t += 128) {
            stats1[t * 2] = 0x7F7FFFFFu; stats1[t * 2 + 1] = 0u;
        }
        for (int t = threadIdx.x; t < 3584; t += 128) bar[t] = 0u;
    }
    float psum = 0.f;
    for (int n = threadIdx.x; n < 896; n += 128) {
        float v = 0.f;
        if (n < 784) {
            float xv = x[b * 784 + n];
            xv = fminf(fmaxf(xv, 0.f), 1.f);
            v = rintf(__fmul_rn(xv, 255.f));
        }
        xr[n] = v;
        psum += v;  // integer-valued, exact in any order
    }
    red[threadIdx.x] = psum;
    __syncthreads();
    for (int w = 64; w >= 1; w >>= 1) {
        if (threadIdx.x < w) red[threadIdx.x] += red[threadIdx.x + w];
        __syncthreads();
    }
    if (threadIdx.x == 0) sx1[b] = red[0];
    if (threadIdx.x < 28) {
        int w = threadIdx.x;
        unsigned words[8] = {0, 0, 0, 0, 0, 0, 0, 0};
#pragma unroll 8
        for (int n = 0; n < 32; ++n) {
            int v = (int)xr[w * 32 + n];
#pragma unroll
            for (int i = 0; i < 8; ++i) words[i] |= ((unsigned)((v >> i) & 1)) << n;
        }
#pragma unroll
        for (int i = 0; i < 8; ++i) xqbT[(i * 28 + w) * 1024 + b] = words[i];
    }
}

// Fused conductance-prep + transpose: writes g1t[n][k*512+f] directly.
__global__ void prepg1t_kernel(const float* __restrict__ w1, const float* __restrict__ noise1,
                               float* __restrict__ g1t)
{
    __shared__ float t[4][32][33];
    const int n0 = blockIdx.x * 32, f0 = blockIdx.y * 32;
    const int tid = threadIdx.x;
    {
        int n = tid & 31, fi = tid >> 5;
#pragma unroll
        for (int p = 0; p < 4; ++p) {
            int f = p * 8 + fi;
            int gn = n0 + n, gf = f0 + f;
            float gv[4] = {0.f, 0.f, 0.f, 0.f};
            if (gn < 784) {
                float w = w1[gf * 784 + gn];
                float Xi = fminf(fmaxf(rintf(__fmul_rn(__fmul_rn(__fadd_rn(w, 1.f), 0.5f), 255.f)),
                                       0.f), 255.f);
                int xi = (int)Xi;
                float4 nz = *(const float4*)&noise1[(gf * 896 + gn) * 4];
                float nzv[4] = {nz.x, nz.y, nz.z, nz.w};
#pragma unroll
                for (int k = 0; k < 4; ++k) {
                    int slc = (xi >> (2 * k)) & 3;
                    float base = __fadd_rn(__fmul_rn((float)slc, 0.9f), 0.3f);
                    float nf = __fadd_rn(1.f, __fmul_rn(0.05f, nzv[k]));
                    gv[k] = __fmul_rn(base, nf);
                }
            }
#pragma unroll
            for (int k = 0; k < 4; ++k) t[k][n][f] = gv[k];
        }
    }
    __syncthreads();
    {
        int f = tid & 31, nn = tid >> 5;
#pragma unroll
        for (int p = 0; p < 4; ++p) {
            int n = p * 8 + nn;
#pragma unroll
            for (int k = 0; k < 4; ++k)
                g1t[(n0 + n) * 2048 + k * 512 + f0 + f] = t[k][n][f];
        }
    }
}

// g2t[n][k][f] layout for layer-2 matmul
__global__ void prepg2_kernel(const float* __restrict__ w3, const float* __restrict__ noise3,
                              float* __restrict__ g2t)
{
    int gid = blockIdx.x * 256 + threadIdx.x;
    if (gid >= 10 * 512) return;
    int f = gid / 512, n = gid % 512;
    float w = w3[f * 512 + n];
    float Xi = fminf(fmaxf(rintf(__fmul_rn(__fmul_rn(__fadd_rn(w, 1.f), 0.5f), 255.f)),
                           0.f), 255.f);
    int xi = (int)Xi;
#pragma unroll
    for (int k = 0; k < 4; ++k) {
        int slc = (xi >> (2 * k)) & 3;
        float base = __fadd_rn(__fmul_rn((float)slc, 0.9f), 0.3f);
        float nf = __fadd_rn(1.f, __fmul_rn(0.05f, noise3[(f * 512 + n) * 4 + k]));
        g2t[n * 40 + k * 10 + f] = __fmul_rn(base, nf);
    }
}

// Layer-1 dummy column from transposed bit-planes: D = 0.3*popc(128 bits).
__global__ void dqpopT_kernel(const unsigned* __restrict__ xqbT, float* __restrict__ Dq)
{
    __shared__ float red[512];
    const int i = blockIdx.x / 7, s = blockIdx.x % 7;
    const int tid = threadIdx.x;
    float D[4];
    float mn = FLTMAX, mx = -FLTMAX;
#pragma unroll
    for (int u = 0; u < 4; ++u) {
        int b = tid + u * 256;
        int c = 0;
#pragma unroll
        for (int w = 0; w < 4; ++w)
            c += __popc(xqbT[(i * 28 + s * 4 + w) * 1024 + b]);
        D[u] = __fmul_rn((float)c, 0.3f);
        mn = fminf(mn, D[u]);
        mx = fmaxf(mx, D[u]);
    }
    red[tid] = mn; red[256 + tid] = mx;
    __syncthreads();
    for (int w = 128; w >= 1; w >>= 1) {
        if (tid < w) {
            red[tid] = fminf(red[tid], red[tid + w]);
            red[256 + tid] = fmaxf(red[256 + tid], red[256 + tid + w]);
        }
        __syncthreads();
    }
    mn = red[0]; mx = red[256];
    float step = __fmul_rn(__fsub_rn(mx, mn), 0.03125f);
    if (step <= 0.f) step = 1.f;
#pragma unroll
    for (int u = 0; u < 4; ++u) {
        int b = tid + u * 256;
        float idx = fminf(fmaxf(floorf(__fdiv_rn(__fsub_rn(D[u], mn), step)), 0.f), 31.f);
        Dq[(i * 7 + s) * 1024 + b] = __fadd_rn(__fmul_rn(idx, step), mn);
    }
}

// Layer-2 dummy column from xqb2 ([i][b][16w] layout).
__global__ void dqpop_kernel(const unsigned* __restrict__ xqb, float* __restrict__ Dq,
                             int S, int wpr)
{
    __shared__ float red[512];
    const int i = blockIdx.x / S, s = blockIdx.x % S;
    const int tid = threadIdx.x;
    float D[4];
    float mn = FLTMAX, mx = -FLTMAX;
#pragma unroll
    for (int u = 0; u < 4; ++u) {
        int b = tid + u * 256;
        uint4 w = *(const uint4*)&xqb[(i * 1024 + b) * wpr + s * 4];
        int c = __popc(w.x) + __popc(w.y) + __popc(w.z) + __popc(w.w);
        D[u] = __fmul_rn((float)c, 0.3f);
        mn = fminf(mn, D[u]);
        mx = fmaxf(mx, D[u]);
    }
    red[tid] = mn; red[256 + tid] = mx;
    __syncthreads();
    for (int w = 128; w >= 1; w >>= 1) {
        if (tid < w) {
            red[tid] = fminf(red[tid], red[tid + w]);
            red[256 + tid] = fmaxf(red[256 + tid], red[256 + tid + w]);
        }
        __syncthreads();
    }
    mn = red[0]; mx = red[256];
    float step = __fmul_rn(__fsub_rn(mx, mn), 0.03125f);
    if (step <= 0.f) step = 1.f;
#pragma unroll
    for (int u = 0; u < 4; ++u) {
        int b = tid + u * 256;
        float idx = fminf(fmaxf(floorf(__fdiv_rn(__fsub_rn(D[u], mn), step)), 0.f), 31.f);
        Dq[(i * S + s) * 1024 + b] = __fadd_rn(__fmul_rn(idx, step), mn);
    }
}

// ---------------------------------------------------------------------------
// Layer-1 persistent GEMM: 512 blocks (2/CU at launch_bounds(256,2)), each
// computing TWO (i,btile) tiles of one col-group per plane; acc as f32x2
// (packed-FMA capable), per-slot 16-block sync, tile-major Pidx stores.
// ---------------------------------------------------------------------------
#define BK 32
__global__ __launch_bounds__(256, 2) void mm1_kernel(
    const unsigned* __restrict__ xqbT, const float* __restrict__ g1t,
    unsigned char* __restrict__ Pidx, unsigned* stats, unsigned* bar)
{
    __shared__ __align__(16) float Bs[BK][132];
    __shared__ unsigned Abits[256];
    __shared__ float red[512];
    __shared__ __align__(16) unsigned stage[2][128 * 33];
    const int tid = threadIdx.x;
    const int pair = blockIdx.x & 31;        // i*4 + bpgrp
    const int i = pair >> 2;                 // 0..7
    const int bp = (pair & 3) * 256;         // row base of the btile PAIR
    const int btile0 = (pair * 2) & 7;       // even btile of the pair
    const int colgrp = blockIdx.x >> 5;      // 0..15
    const int colBase = colgrp * 128;
    const int tx = tid & 15, ty = tid >> 4;
    const int aB = tid >> 5;          // 0..7  (B rows: u*8 + aB)
    const int eB = (tid & 31) << 2;   // 0..124
    const int k = colgrp >> 2;
    // store-phase mapping: lane l -> 8 rows x 8 chunks of 16B (1KB/wave-instr)
    const int wv = tid >> 6, ln = tid & 63;
    const int rsub = ln >> 3, chunk = ln & 7;

    for (int s = 0; s < 7; ++s) {
        // prefetch chunk 0  (xqbT layout: [i][w][b], w = s*4 + chunk)
        float4 pB[4];
#pragma unroll
        for (int u = 0; u < 4; ++u)
            pB[u] = *(const float4*)&g1t[(s * 128 + u * 8 + aB) * 2048 + colBase + eB];
        unsigned pAw = xqbT[(i * 28 + s * 4) * 1024 + bp + tid];

        // acc[q][u][p]: p-th f32x2 pair = cols (v=2p, 2p+1); 128 floats.
        f32x2 acc[2][8][4] = {};

        for (int ac = 0; ac < 4; ++ac) {
            __syncthreads();
#pragma unroll
            for (int u = 0; u < 4; ++u)
                *(float4*)&Bs[u * 8 + aB][eB] = pB[u];
            Abits[tid] = pAw;
            __syncthreads();

            if (ac < 3) {
                const int n0 = s * 128 + (ac + 1) * BK;
#pragma unroll
                for (int u = 0; u < 4; ++u)
                    pB[u] = *(const float4*)&g1t[(n0 + u * 8 + aB) * 2048 + colBase + eB];
                pAw = xqbT[(i * 28 + s * 4 + ac + 1) * 1024 + bp + tid];
            }

            unsigned wrd[2][8];
#pragma unroll
            for (int q = 0; q < 2; ++q)
#pragma unroll
                for (int u = 0; u < 4; ++u) {
                    wrd[q][u]     = Abits[q * 128 + (ty << 2) + u];
                    wrd[q][4 + u] = Abits[q * 128 + 64 + (ty << 2) + u];
                }

#pragma unroll 4
            for (int a = 0; a < BK; ++a) {
                float4 b0 = *(const float4*)&Bs[a][(tx << 2)];
                float4 b1 = *(const float4*)&Bs[a][64 + (tx << 2)];
                f32x2 br[4];
                br[0] = (f32x2){b0.x, b0.y}; br[1] = (f32x2){b0.z, b0.w};
                br[2] = (f32x2){b1.x, b1.y}; br[3] = (f32x2){b1.z, b1.w};
#pragma unroll
                for (int q = 0; q < 2; ++q)
#pragma unroll
                    for (int u = 0; u < 8; ++u) {
                        float ab = (float)((wrd[q][u] >> a) & 1u);
                        f32x2 abv = {ab, ab};
#pragma unroll
                        for (int p = 0; p < 4; ++p)
                            acc[q][u][p] = __builtin_elementwise_fma(abv, br[p], acc[q][u][p]);
                    }
            }
        }

        // block min/max over BOTH tiles (same stats slot: same s,i,k)
        float mn = acc[0][0][0].x, mx = acc[0][0][0].x;
#pragma unroll
        for (int q = 0; q < 2; ++q)
#pragma unroll
            for (int u = 0; u < 8; ++u)
#pragma unroll
                for (int p = 0; p < 4; ++p) {
                    mn = fminf(mn, acc[q][u][p].x); mx = fmaxf(mx, acc[q][u][p].x);
                    mn = fminf(mn, acc[q][u][p].y); mx = fmaxf(mx, acc[q][u][p].y);
                }
        red[tid] = mn; red[256 + tid] = mx;
        __syncthreads();
        for (int w = 128; w >= 1; w >>= 1) {
            if (tid < w) {
                red[tid] = fminf(red[tid], red[tid + w]);
                red[256 + tid] = fmaxf(red[256 + tid], red[256 + tid + w]);
            }
            __syncthreads();
        }
        const int slot = ((s * 8 + i) * 4 + k);
        if (tid == 0) {
            atomicMin(&stats[slot * 2],     __float_as_uint(red[0]));
            atomicMax(&stats[slot * 2 + 1], __float_as_uint(red[256]));
        }

        // per-slot sync: only the 16 blocks sharing (s,i,k) rendezvous.
        slot_barrier(&bar[slot * 16], 16u);

        // COHERENT read at the atomics' coherence point.
        unsigned mnu = __hip_atomic_load(&stats[slot * 2],     __ATOMIC_RELAXED,
                                         __HIP_MEMORY_SCOPE_AGENT);
        unsigned mxu = __hip_atomic_load(&stats[slot * 2 + 1], __ATOMIC_RELAXED,
                                         __HIP_MEMORY_SCOPE_AGENT);
        float qmn = __uint_as_float(mnu);
        float qmx = __uint_as_float(mxu);
        float step = __fmul_rn(__fsub_rn(qmx, qmn), 0.03125f);
        if (step <= 0.f) step = 1.f;

        // quantize in-register -> pack 4 indices/word -> LDS stage (per tile)
#pragma unroll
        for (int q = 0; q < 2; ++q)
#pragma unroll
            for (int uh = 0; uh < 2; ++uh)
#pragma unroll
                for (int u = 0; u < 4; ++u) {
                    int rr = uh * 64 + (ty << 2) + u;
#pragma unroll
                    for (int vh = 0; vh < 2; ++vh) {
                        f32x2 e0 = acc[q][uh * 4 + u][vh * 2];
                        f32x2 e1 = acc[q][uh * 4 + u][vh * 2 + 1];
                        float ix;
                        unsigned pack;
                        ix = fminf(fmaxf(floorf(__fdiv_rn(__fsub_rn(e0.x, qmn), step)), 0.f), 31.f);
                        pack = (unsigned)(int)ix;
                        ix = fminf(fmaxf(floorf(__fdiv_rn(__fsub_rn(e0.y, qmn), step)), 0.f), 31.f);
                        pack |= (unsigned)(int)ix << 8;
                        ix = fminf(fmaxf(floorf(__fdiv_rn(__fsub_rn(e1.x, qmn), step)), 0.f), 31.f);
                        pack |= (unsigned)(int)ix << 16;
                        ix = fminf(fmaxf(floorf(__fdiv_rn(__fsub_rn(e1.y, qmn), step)), 0.f), 31.f);
                        pack |= (unsigned)(int)ix << 24;
                        stage[q][rr * 33 + vh * 16 + tx] = pack;
                    }
                }
        __syncthreads();

        // tile-major contiguous write: 2 private 16KB tiles, each wave
        // instruction writes 1KB contiguous.
#pragma unroll
        for (int q = 0; q < 2; ++q) {
            unsigned char* tbase = Pidx +
                ((size_t)(((s * 8 + i) * 16 + colgrp) * 8 + btile0 + q)) * 16384;
#pragma unroll
            for (int t = 0; t < 4; ++t) {
                int rr = t * 32 + wv * 8 + rsub;
                const unsigned* sp = &stage[q][rr * 33 + chunk * 4];
                uint4 v = make_uint4(sp[0], sp[1], sp[2], sp[3]);
                *(uint4*)&tbase[rr * 128 + chunk * 16] = v;
            }
        }
        // stage not rewritten until after this block's next __syncthreads
        // sequence in the following plane; intra-block ordering suffices.
        __syncthreads();
    }
}

// fold1: reconstruct pq = idx*step + mn (exact same fp32 ops as before) and
// run the full original chain. Block per b, 512 threads.
// Pidx element (s,i,b,f,kk): tile = ((s*8+i)*16 + kk*4 + (f>>7))*8 + (b>>7);
// byte = tile*16384 + (b&127)*128 + (f&127).
__global__ void fold1_kernel(const unsigned char* __restrict__ Pidx,
                             const unsigned* __restrict__ stats,
                             const float* __restrict__ Dq1, const float* __restrict__ sx1,
                             float* __restrict__ xq2, unsigned* __restrict__ xqb2,
                             float* __restrict__ sx2)
{
    __shared__ float red[512];
    __shared__ float dt;
    __shared__ float2 st[224];
    int b = blockIdx.x;
    int f = threadIdx.x;                      // 0..511
    if (f < 224) {
        float mn = __uint_as_float(stats[f * 2]);
        float mx = __uint_as_float(stats[f * 2 + 1]);
        float step = __fmul_rn(__fsub_rn(mx, mn), 0.03125f);
        if (step <= 0.f) step = 1.f;
        st[f] = make_float2(mn, step);
    }
    if (f == 0) {
        float sd = 0.f;
        for (int i = 0; i < 8; ++i) {
            float sc = (float)(85 << i);
            for (int ss = 0; ss < 7; ++ss) sd = fmaf(Dq1[(i * 7 + ss) * 1024 + b], sc, sd);
        }
        dt = sd;
    }
    __syncthreads();
    const int fhi = f >> 7, fl = f & 127;
    const unsigned char* pb = Pidx + (size_t)(b >> 7) * 16384
                                   + (size_t)(b & 127) * 128 + fl;
    float accR = 0.f;
    for (int s = 0; s < 7; ++s) {
        float sum = 0.f;
        for (int i = 0; i < 8; ++i) {
            const int si16 = (s * 8 + i) * 16;
#pragma unroll
            for (int kk = 0; kk < 4; ++kk) {
                float2 ms = st[((s * 8 + i) << 2) + kk];
                float ixv = (float)pb[(size_t)(si16 + kk * 4 + fhi) * 131072];
                float pq = __fadd_rn(__fmul_rn(ixv, ms.y), ms.x);
                sum = fmaf(pq, (float)(1 << (i + 2 * kk)), sum);
            }
        }
        accR = __fadd_rn(accR, sum);
    }
    float total = __fsub_rn(accR, dt);
    float acc = __fdiv_rn(total, 0.9f);
    float o = __fsub_rn(__fdiv_rn(__fmul_rn(2.f, acc), 65025.f), __fdiv_rn(sx1[b], 255.f));
    float h = tanhf(o);
    h = fminf(fmaxf(h, 0.f), 1.f);
    float code = rintf(__fmul_rn(h, 255.f));
    xq2[b * 512 + f] = code;
    int ci = (int)code;
    int lane = f & 63;
#pragma unroll
    for (int i = 0; i < 8; ++i) {
        unsigned long long m = __ballot((ci >> i) & 1);
        if ((lane & 31) == 0) {
            unsigned wv = (lane & 32) ? (unsigned)(m >> 32) : (unsigned)m;
            xqb2[(i * 1024 + b) * 16 + (f >> 5)] = wv;
        }
    }
    red[f] = code;
    __syncthreads();
    for (int w = 256; w >= 1; w >>= 1) {
        if (f < w) red[f] += red[f + w];
        __syncthreads();
    }
    if (f == 0) sx2[b] = red[0];
}

// Layer-2 matmul: thread per (s,b,f), 32 accumulators (i,k)
__global__ void mm2_kernel(const float* __restrict__ xq2, const float* __restrict__ g2t,
                           float* __restrict__ P2)
{
    int gid = blockIdx.x * 256 + threadIdx.x;  // 40960
    if (gid >= 40960) return;
    int f = gid % 10;
    int b = (gid / 10) & 1023;
    int s = gid / 10240;
    float acc[8][4] = {};
    for (int a = 0; a < 128; ++a) {
        int n = s * 128 + a;
        int xi = (int)xq2[b * 512 + n];
        float g0 = g2t[n * 40 + f];
        float gA = g2t[n * 40 + 10 + f];
        float gB = g2t[n * 40 + 20 + f];
        float gC = g2t[n * 40 + 30 + f];
#pragma unroll
        for (int i = 0; i < 8; ++i) {
            float bi = (float)((xi >> i) & 1);
            acc[i][0] = fmaf(bi, g0, acc[i][0]);
            acc[i][1] = fmaf(bi, gA, acc[i][1]);
            acc[i][2] = fmaf(bi, gB, acc[i][2]);
            acc[i][3] = fmaf(bi, gC, acc[i][3]);
        }
    }
#pragma unroll
    for (int i = 0; i < 8; ++i)
#pragma unroll
        for (int k = 0; k < 4; ++k)
            P2[(size_t)((s * 8 + i) * 4 + k) * 10240 + b * 10 + f] = acc[i][k];
}

__global__ void stat2_kernel(const float* __restrict__ P2, float2* __restrict__ stats2)
{
    __shared__ float red[512];
    int p = blockIdx.x;  // 128 planes
    int tid = threadIdx.x;
    float mn = FLTMAX, mx = -FLTMAX;
    for (int t = tid; t < 10240; t += 256) {
        float v = P2[(size_t)p * 10240 + t];
        mn = fminf(mn, v); mx = fmaxf(mx, v);
    }
    red[tid] = mn; red[256 + tid] = mx;
    __syncthreads();
    for (int w = 128; w >= 1; w >>= 1) {
        if (tid < w) {
            red[tid] = fminf(red[tid], red[tid + w]);
            red[256 + tid] = fmaxf(red[256 + tid], red[256 + tid + w]);
        }
        __syncthreads();
    }
    if (tid == 0) {
        float step = __fmul_rn(__fsub_rn(red[256], red[0]), 0.03125f);
        if (step <= 0.f) step = 1.f;
        stats2[p] = make_float2(red[0], step);
    }
}

// dterm2[b] computed inline per thread (exact i-outer/s-inner chain).
__global__ void out2_kernel(const float* __restrict__ P2, const float2* __restrict__ stats2,
                            const float* __restrict__ Dq2, const float* __restrict__ sx2,
                            float* __restrict__ out)
{
    int gid = blockIdx.x * 256 + threadIdx.x;  // 10240
    if (gid >= 10240) return;
    int b = gid / 10;
    float dt = 0.f;
    for (int i = 0; i < 8; ++i) {
        float sc = (float)(85 << i);
        for (int s = 0; s < 4; ++s) dt = fmaf(Dq2[(i * 4 + s) * 1024 + b], sc, dt);
    }
    float sum = 0.f;
    for (int s = 0; s < 4; ++s)
        for (int i = 0; i < 8; ++i)
#pragma unroll
            for (int k = 0; k < 4; ++k) {
                int p = (s * 8 + i) * 4 + k;
                float2 st = stats2[p];
                float val = P2[(size_t)p * 10240 + gid];
                float idx = fminf(fmaxf(floorf(__fdiv_rn(__fsub_rn(val, st.x), st.y)), 0.f), 31.f);
                float pq = __fadd_rn(__fmul_rn(idx, st.y), st.x);
                sum = fmaf(pq, (float)(1 << (i + 2 * k)), sum);
            }
    float total = __fsub_rn(sum, dt);
    float acc = __fdiv_rn(total, 0.9f);
    out[gid] = __fsub_rn(__fdiv_rn(__fmul_rn(2.f, acc), 65025.f), __fdiv_rn(sx2[b], 255.f));
}

extern "C" void kernel_launch(void* const* d_in, const int* in_sizes, int n_in,
                              void* d_out, int out_size, void* d_ws, size_t ws_size,
                              hipStream_t stream)
{
    const float* x      = (const float*)d_in[0];
    const float* w1     = (const float*)d_in[1];
    const float* w3     = (const float*)d_in[2];
    const float* noise1 = (const float*)d_in[3];
    const float* noise3 = (const float*)d_in[4];
    float* out = (float*)d_out;
    float* ws  = (float*)d_ws;

    // ws layout (float offsets)
    float*         g1t    = ws + 0;              // 896*2048
    float*         xq2    = ws + 1835008;        // 1024*512
    float*         P2     = ws + 2359296;        // 128*10240
    float*         g2t    = ws + 3670016;        // 512*40
    float*         Dq1    = ws + 3690496;        // 56*1024
    float*         Dq2    = ws + 3747840;        // 32*1024
    float*         sx1    = ws + 3780608;        // 1024
    float*         sx2    = ws + 3781632;        // 1024
    float2*        stats2 = (float2*)(ws + 3782656);    // 128 pairs
    unsigned*      stats1 = (unsigned*)(ws + 3782912);  // 224*2 words
    unsigned*      xqbT   = (unsigned*)(ws + 3783424);  // 8*28*1024 words
    unsigned*      xqb2   = (unsigned*)(ws + 4012800);  // 8*1024*16 words
    unsigned char* Pidx   = (unsigned char*)(ws + 4143872);  // 7168 tiles * 16KB
    unsigned*      bar    = (unsigned*)(ws + 33504256); // 3584 words (after Pidx)

    prep1_kernel<<<1024, 128, 0, stream>>>(x, sx1, xqbT, stats1, bar);
    prepg1t_kernel<<<dim3(28, 16), 256, 0, stream>>>(w1, noise1, g1t);
    dqpopT_kernel<<<56, 256, 0, stream>>>(xqbT, Dq1);

    mm1_kernel<<<512, 256, 0, stream>>>(xqbT, g1t, Pidx, stats1, bar);

    fold1_kernel<<<1024, 512, 0, stream>>>(Pidx, stats1, Dq1, sx1, xq2, xqb2, sx2);
    prepg2_kernel<<<20, 256, 0, stream>>>(w3, noise3, g2t);
    dqpop_kernel<<<32, 256, 0, stream>>>(xqb2, Dq2, 4, 16);
    mm2_kernel<<<160, 256, 0, stream>>>(xq2, g2t, P2);
    stat2_kernel<<<128, 256, 0, stream>>>(P2, stats2);
    out2_kernel<<<40, 256, 0, stream>>>(P2, stats2, Dq2, sx2, out);
}